// Round 1
// baseline (631.058 us; speedup 1.0000x reference)
//
#include <hip/hip_runtime.h>
#include <hip/hip_bf16.h>

// MinGRU: L=2 layers of  h_t = (1-z_t) h_{t-1} + z_t g(pre_t),
//   z = sigmoid(x@Wz^T + bz), pre = x@Wh^T + bh, g(x)= x+0.5 (x>=0) else sigmoid(x)
// Strategy: bf16 MFMA GEMMs (fused gate epilogue -> interleaved (coeff,value) float2),
// then 3-phase chunked linear scan over S.

#define L_ 2
#define B_ 8
#define S_ 2048
#define D_ 1024
#define H_ 1024
#define M_ (B_*S_)     // 16384 rows
#define NC 16          // chunks per sequence
#define CL (S_/NC)     // 128 steps per chunk

typedef __bf16 bf16x8 __attribute__((ext_vector_type(8)));
typedef float  f32x4  __attribute__((ext_vector_type(4)));

__device__ __forceinline__ ushort f2bf(float f) {
    union { __hip_bfloat16 h; ushort u; } c;
    c.h = __float2bfloat16(f);   // RNE
    return c.u;
}

__global__ __launch_bounds__(256) void cast_f32_bf16(const float* __restrict__ in,
                                                     ushort* __restrict__ out, int n4) {
    int i = blockIdx.x * 256 + threadIdx.x;
    if (i >= n4) return;
    float4 v = ((const float4*)in)[i];
    ushort4 o;
    o.x = f2bf(v.x); o.y = f2bf(v.y); o.z = f2bf(v.z); o.w = f2bf(v.w);
    ((ushort4*)out)[i] = o;
}

// C = A(bf16,[M,K]) * W(bf16,[N,K])^T + bias, fused gate epilogue.
// mode 0: cv[m*H+n] = (sigmoid(-k), sigmoid(k))        (coeff, z)
// mode 1: cv[m*H+n].y *= g(pre)                        (value = z*g)
__global__ __launch_bounds__(256) void gemm_gate(const ushort* __restrict__ A,
                                                 const ushort* __restrict__ W,
                                                 const float* __restrict__ bias,
                                                 float2* __restrict__ cv,
                                                 const int mode)
{
    __shared__ __align__(16) ushort As[128*64];
    __shared__ __align__(16) ushort Ws[128*64];
    const int t    = threadIdx.x;
    const int lane = t & 63;
    const int wave = t >> 6;
    const int m0 = (int)(blockIdx.x >> 3) * 128;   // 128 m-blocks
    const int n0 = (int)(blockIdx.x & 7) * 128;    // 8 n-blocks
    const int wm = (wave >> 1) * 64;
    const int wn = (wave & 1) * 64;
    const int srow = t >> 3;         // staging: 32 rows per iter
    const int scol = (t & 7) * 8;    // 8 bf16 (16B) per thread

    f32x4 acc[4][4] = {};

    const int lrow = lane & 15;
    const int lq8  = (lane >> 4) * 8;

    for (int kb = 0; kb < D_; kb += 64) {
        __syncthreads();
        #pragma unroll
        for (int i = 0; i < 4; ++i) {
            int r = i*32 + srow;
            *(uint4*)&As[r*64 + scol] = *(const uint4*)&A[(m0 + r)*D_ + kb + scol];
            *(uint4*)&Ws[r*64 + scol] = *(const uint4*)&W[(n0 + r)*D_ + kb + scol];
        }
        __syncthreads();
        #pragma unroll
        for (int kk = 0; kk < 64; kk += 32) {
            bf16x8 af[4], bf[4];
            #pragma unroll
            for (int mt = 0; mt < 4; ++mt) {
                uint4 u = *(const uint4*)&As[(wm + mt*16 + lrow)*64 + kk + lq8];
                af[mt] = __builtin_bit_cast(bf16x8, u);
            }
            #pragma unroll
            for (int nt = 0; nt < 4; ++nt) {
                uint4 u = *(const uint4*)&Ws[(wn + nt*16 + lrow)*64 + kk + lq8];
                bf[nt] = __builtin_bit_cast(bf16x8, u);
            }
            #pragma unroll
            for (int mt = 0; mt < 4; ++mt)
                #pragma unroll
                for (int nt = 0; nt < 4; ++nt)
                    acc[mt][nt] = __builtin_amdgcn_mfma_f32_16x16x32_bf16(
                        af[mt], bf[nt], acc[mt][nt], 0, 0, 0);
        }
    }

    // Epilogue. C/D layout: col = lane&15, row = (lane>>4)*4 + reg  [m89-verified]
    const int colq = lane & 15;
    const int rowq = (lane >> 4) * 4;
    #pragma unroll
    for (int nt = 0; nt < 4; ++nt) {
        const int n = n0 + wn + nt*16 + colq;
        const float bv = bias[n];
        #pragma unroll
        for (int mt = 0; mt < 4; ++mt) {
            #pragma unroll
            for (int r = 0; r < 4; ++r) {
                const int m = m0 + wm + mt*16 + rowq + r;
                float v = acc[mt][nt][r] + bv;
                size_t idx = (size_t)m * H_ + n;
                if (mode == 0) {
                    float e   = __expf(-fabsf(v));
                    float inv = 1.0f / (1.0f + e);
                    float z   = (v >= 0.f) ? inv     : e * inv;
                    float cf  = (v >= 0.f) ? e * inv : inv;
                    cv[idx] = make_float2(cf, z);
                } else {
                    float g;
                    if (v >= 0.f) g = v + 0.5f;
                    else { float e = __expf(v); g = e / (1.0f + e); }
                    cv[idx].y *= g;
                }
            }
        }
    }
}

// Phase A: per (b, chunk, h) compute affine composition over the chunk:
// h_out = a * h_in + bv  where a = prod coeff, bv = folded values.
__global__ __launch_bounds__(256) void scan_chunk_reduce(const float2* __restrict__ cv,
                                                         float* __restrict__ Ac,
                                                         float* __restrict__ Bc)
{
    int q = blockIdx.x * 256 + threadIdx.x;   // 0 .. B*NC*H-1
    int h = q & (H_-1);
    int c = (q >> 10) & (NC-1);
    int b = q >> 14;
    const float2* p = cv + ((size_t)(b*S_ + c*CL) * H_ + h);
    float a = 1.f, bv = 0.f;
    for (int tt = 0; tt < CL; ++tt) {
        float2 e = p[(size_t)tt * H_];
        bv = fmaf(e.x, bv, e.y);
        a *= e.x;
    }
    Ac[q] = a;
    Bc[q] = bv;
}

// Phase B: per (b,h) scan over the NC chunk-affines; emit incoming h per chunk.
__global__ __launch_bounds__(256) void scan_chunk_combine(const float* __restrict__ Ac,
                                                          const float* __restrict__ Bc,
                                                          float* __restrict__ hin)
{
    int q = blockIdx.x * 256 + threadIdx.x;   // 0 .. B*H-1
    int h = q & (H_-1);
    int b = q >> 10;
    float hcur = 0.5f;                        // h0 = g(0) = 0.5
    #pragma unroll
    for (int c = 0; c < NC; ++c) {
        int idx = (b*NC + c)*H_ + h;
        hin[idx] = hcur;
        hcur = fmaf(Ac[idx], hcur, Bc[idx]);
    }
}

// Phase C: re-scan each chunk with known incoming h, emit outputs.
// write_bf16=1 -> bf16 into outb (next layer's GEMM input); else fp32 into outf.
__global__ __launch_bounds__(256) void scan_emit(const float2* __restrict__ cv,
                                                 const float* __restrict__ hin,
                                                 float* __restrict__ outf,
                                                 ushort* __restrict__ outb,
                                                 const int write_bf16)
{
    int q = blockIdx.x * 256 + threadIdx.x;
    int h = q & (H_-1);
    int c = (q >> 10) & (NC-1);
    int b = q >> 14;
    size_t base = (size_t)(b*S_ + c*CL) * H_ + h;
    const float2* p = cv + base;
    float hcur = hin[q];
    for (int tt = 0; tt < CL; ++tt) {
        float2 e = p[(size_t)tt * H_];
        hcur = fmaf(e.x, hcur, e.y);
        if (write_bf16) outb[base + (size_t)tt * H_] = f2bf(hcur);
        else            outf[base + (size_t)tt * H_] = hcur;
    }
}

extern "C" void kernel_launch(void* const* d_in, const int* in_sizes, int n_in,
                              void* d_out, int out_size, void* d_ws, size_t ws_size,
                              hipStream_t stream)
{
    const float* x  = (const float*)d_in[0];
    const float* Wz = (const float*)d_in[1];
    const float* bz = (const float*)d_in[2];
    const float* Wh = (const float*)d_in[3];
    const float* bh = (const float*)d_in[4];
    float* out = (float*)d_out;

    // workspace layout (~170 MiB):
    ushort* xb  = (ushort*)d_ws;                      // M*D bf16        (32 MiB)
    ushort* wzb = xb  + (size_t)M_*D_;                // L*H*D bf16      (4 MiB)
    ushort* whb = wzb + (size_t)L_*H_*D_;             // L*H*D bf16      (4 MiB)
    float2* cv  = (float2*)(whb + (size_t)L_*H_*D_);  // M*H float2      (128 MiB)
    float*  Ac  = (float*)(cv + (size_t)M_*H_);       // B*NC*H          (0.5 MiB)
    float*  Bc  = Ac + B_*NC*H_;                      // B*NC*H
    float*  hin = Bc + B_*NC*H_;                      // B*NC*H

    cast_f32_bf16<<<(M_*D_/4)/256, 256, 0, stream>>>(x, xb, M_*D_/4);
    cast_f32_bf16<<<(L_*H_*D_/4)/256, 256, 0, stream>>>(Wz, wzb, L_*H_*D_/4);
    cast_f32_bf16<<<(L_*H_*D_/4)/256, 256, 0, stream>>>(Wh, whb, L_*H_*D_/4);

    const int gemm_grid = (M_/128) * (H_/128);   // 128*8 = 1024 blocks
    for (int l = 0; l < L_; ++l) {
        gemm_gate<<<gemm_grid, 256, 0, stream>>>(xb, wzb + (size_t)l*H_*D_, bz + l*H_, cv, 0);
        gemm_gate<<<gemm_grid, 256, 0, stream>>>(xb, whb + (size_t)l*H_*D_, bh + l*H_, cv, 1);
        scan_chunk_reduce<<<(B_*NC*H_)/256, 256, 0, stream>>>(cv, Ac, Bc);
        scan_chunk_combine<<<(B_*H_)/256, 256, 0, stream>>>(Ac, Bc, hin);
        // layer 0 emits bf16 into xb (next layer's input); layer 1 emits fp32 output
        scan_emit<<<(B_*NC*H_)/256, 256, 0, stream>>>(cv, hin, out, xb, (l == 0) ? 1 : 0);
    }
}

// Round 2
// 446.588 us; speedup vs baseline: 1.4131x; 1.4131x over previous
//
#include <hip/hip_runtime.h>
#include <hip/hip_bf16.h>

// MinGRU: L=2 layers of  h_t = (1-z_t) h_{t-1} + z_t g(pre_t)
// R2: fused dual-W MFMA GEMM (async global_load_lds staging), fp16 (coeff,value),
// chunk-reduce fused into GEMM epilogue, then combine + emit.

#define L_ 2
#define B_ 8
#define S_ 2048
#define D_ 1024
#define H_ 1024
#define M_ (B_*S_)     // 16384
#define NC 16          // chunks per sequence
#define CL (S_/NC)     // 128 steps per chunk (== GEMM m-tile!)

typedef __bf16    bf16x8 __attribute__((ext_vector_type(8)));
typedef float     f32x4  __attribute__((ext_vector_type(4)));
typedef _Float16  h2     __attribute__((ext_vector_type(2)));

__device__ __forceinline__ ushort f2bf(float f) {
    union { __hip_bfloat16 h; ushort u; } c;
    c.h = __float2bfloat16(f);   // RNE
    return c.u;
}

__device__ __forceinline__ void async16(const void* g, void* l) {
    __builtin_amdgcn_global_load_lds(
        (const __attribute__((address_space(1))) unsigned int*)g,
        (__attribute__((address_space(3))) unsigned int*)l, 16, 0, 0);
}

__global__ __launch_bounds__(256) void cast_f32_bf16(const float* __restrict__ in,
                                                     ushort* __restrict__ out, int n4) {
    int i = blockIdx.x * 256 + threadIdx.x;
    if (i >= n4) return;
    float4 v = ((const float4*)in)[i];
    ushort4 o;
    o.x = f2bf(v.x); o.y = f2bf(v.y); o.z = f2bf(v.z); o.w = f2bf(v.w);
    ((ushort4*)out)[i] = o;
}

// Fused: k = A@Wz^T+bz, pre = A@Wh^T+bh ; cv = (sigmoid(-k), sigmoid(k)*g(pre)) as fp16x2.
// Tile 128m x 64n; m-tile == one (batch, chunk); epilogue also composes the chunk affine
// (fp32) -> Ac, Bc.
__global__ __launch_bounds__(256) void gemm_fused(const ushort* __restrict__ A,
                                                  const ushort* __restrict__ Wz,
                                                  const ushort* __restrict__ Wh,
                                                  const float* __restrict__ bz,
                                                  const float* __restrict__ bh,
                                                  h2* __restrict__ cv,
                                                  float* __restrict__ Ac,
                                                  float* __restrict__ Bc)
{
    __shared__ __align__(16) ushort sm[16384];       // 32 KiB
    ushort* As = sm;            // 128 x 64
    ushort* Zs = sm + 8192;     //  64 x 64
    ushort* Hs = sm + 12288;    //  64 x 64

    const int t    = threadIdx.x;
    const int lane = t & 63;
    const int wave = t >> 6;
    const int mblk = (int)blockIdx.x >> 4;           // 128 m-blocks (nblk fast: A L2 reuse)
    const int nblk = (int)blockIdx.x & 15;           // 16 n-blocks
    const int m0 = mblk * 128;
    const int n0 = nblk * 64;
    const int wm = (wave >> 1) * 64;                 // 0 / 64
    const int wn = (wave & 1) * 32;                  // 0 / 32

    const int srow = lane >> 3;                      // staging: 8 rows / wave / call
    const int scol = (lane & 7) * 8;                 // 8 bf16 = 16 B per lane

    f32x4 accz[4][2] = {};
    f32x4 acch[4][2] = {};
    const int lrow = lane & 15;
    const int lq8  = (lane >> 4) * 8;

    for (int kb = 0; kb < D_; kb += 64) {
        __syncthreads();
        #pragma unroll
        for (int i = 0; i < 4; ++i) {                // A: 128 rows
            int r = i*32 + wave*8;
            async16(&A[(size_t)(m0 + r + srow)*D_ + kb + scol], &As[r*64]);
        }
        #pragma unroll
        for (int i = 0; i < 2; ++i) {                // Wz, Wh: 64 rows each
            int r = i*32 + wave*8;
            async16(&Wz[(size_t)(n0 + r + srow)*D_ + kb + scol], &Zs[r*64]);
            async16(&Wh[(size_t)(n0 + r + srow)*D_ + kb + scol], &Hs[r*64]);
        }
        __syncthreads();                             // drains vmcnt -> LDS valid
        #pragma unroll
        for (int kk = 0; kk < 64; kk += 32) {
            bf16x8 af[4];
            #pragma unroll
            for (int mt = 0; mt < 4; ++mt) {
                uint4 u = *(const uint4*)&As[(wm + mt*16 + lrow)*64 + kk + lq8];
                af[mt] = __builtin_bit_cast(bf16x8, u);
            }
            #pragma unroll
            for (int nt = 0; nt < 2; ++nt) {
                uint4 uz = *(const uint4*)&Zs[(wn + nt*16 + lrow)*64 + kk + lq8];
                uint4 uh = *(const uint4*)&Hs[(wn + nt*16 + lrow)*64 + kk + lq8];
                bf16x8 zb = __builtin_bit_cast(bf16x8, uz);
                bf16x8 hb = __builtin_bit_cast(bf16x8, uh);
                #pragma unroll
                for (int mt = 0; mt < 4; ++mt) {
                    accz[mt][nt] = __builtin_amdgcn_mfma_f32_16x16x32_bf16(af[mt], zb, accz[mt][nt], 0, 0, 0);
                    acch[mt][nt] = __builtin_amdgcn_mfma_f32_16x16x32_bf16(af[mt], hb, acch[mt][nt], 0, 0, 0);
                }
            }
        }
    }

    __syncthreads();                                 // all MFMA LDS reads done; reuse LDS
    float2* seg = (float2*)sm;                       // [32 segs][stride 65] float2 (~16.6 KiB)

    // C/D layout [m89-verified]: col = lane&15, row = (lane>>4)*4 + reg
    const int colq = lane & 15;
    const int rowq = (lane >> 4) * 4;
    #pragma unroll
    for (int nt = 0; nt < 2; ++nt) {
        const int n = n0 + wn + nt*16 + colq;
        const float bzv = bz[n];
        const float bhv = bh[n];
        #pragma unroll
        for (int mt = 0; mt < 4; ++mt) {
            float a = 1.f, bb = 0.f;                 // affine over this lane's 4 rows
            #pragma unroll
            for (int r = 0; r < 4; ++r) {
                const int m = m0 + wm + mt*16 + rowq + r;
                float k = accz[mt][nt][r] + bzv;
                float p = acch[mt][nt][r] + bhv;
                float e   = __expf(-fabsf(k));
                float inv = 1.0f / (1.0f + e);
                float z   = (k >= 0.f) ? inv     : e * inv;
                float c   = (k >= 0.f) ? e * inv : inv;
                float g;
                if (p >= 0.f) g = p + 0.5f;
                else { float eg = __expf(p); g = eg / (1.0f + eg); }
                float v = z * g;
                h2 hv; hv[0] = (_Float16)c; hv[1] = (_Float16)v;
                cv[(size_t)m * H_ + n] = hv;
                bb = fmaf(c, bb, v);                 // apply step after current affine
                a *= c;
            }
            const int sidx = (wm >> 2) + mt*4 + (rowq >> 2);   // 0..31, ordered by s
            seg[sidx*65 + wn + nt*16 + colq] = make_float2(a, bb);
        }
    }
    __syncthreads();
    if (t < 64) {                                    // compose 32 segments per column
        float a = 1.f, bb = 0.f;
        #pragma unroll
        for (int s = 0; s < 32; ++s) {
            float2 e = seg[s*65 + t];
            bb = fmaf(e.x, bb, e.y);
            a *= e.x;
        }
        const int b     = m0 >> 11;                  // S = 2048
        const int chunk = (m0 >> 7) & (NC - 1);
        const int q = (b*NC + chunk)*H_ + n0 + t;
        Ac[q] = a; Bc[q] = bb;
    }
}

// Scan over the NC chunk-affines per (b,h); emit incoming h per chunk.
__global__ __launch_bounds__(256) void scan_chunk_combine(const float* __restrict__ Ac,
                                                          const float* __restrict__ Bc,
                                                          float* __restrict__ hin)
{
    int q = blockIdx.x * 256 + threadIdx.x;          // 0 .. B*H-1
    int h = q & (H_-1);
    int b = q >> 10;
    float hcur = 0.5f;                               // h0 = g(0) = 0.5
    #pragma unroll
    for (int c = 0; c < NC; ++c) {
        int idx = (b*NC + c)*H_ + h;
        hin[idx] = hcur;
        hcur = fmaf(Ac[idx], hcur, Bc[idx]);
    }
}

// Re-scan each chunk with known incoming h, emit outputs.
__global__ __launch_bounds__(256) void scan_emit(const h2* __restrict__ cv,
                                                 const float* __restrict__ hin,
                                                 float* __restrict__ outf,
                                                 ushort* __restrict__ outb,
                                                 const int write_bf16)
{
    int q = blockIdx.x * 256 + threadIdx.x;
    int h = q & (H_-1);
    int c = (q >> 10) & (NC-1);
    int b = q >> 14;
    size_t base = (size_t)(b*S_ + c*CL) * H_ + h;
    const h2* p = cv + base;
    float hcur = hin[q];
    for (int tt = 0; tt < CL; ++tt) {
        h2 e = p[(size_t)tt * H_];
        hcur = fmaf((float)e[0], hcur, (float)e[1]);
        if (write_bf16) outb[base + (size_t)tt * H_] = f2bf(hcur);
        else            outf[base + (size_t)tt * H_] = hcur;
    }
}

extern "C" void kernel_launch(void* const* d_in, const int* in_sizes, int n_in,
                              void* d_out, int out_size, void* d_ws, size_t ws_size,
                              hipStream_t stream)
{
    const float* x  = (const float*)d_in[0];
    const float* Wz = (const float*)d_in[1];
    const float* bz = (const float*)d_in[2];
    const float* Wh = (const float*)d_in[3];
    const float* bh = (const float*)d_in[4];
    float* out = (float*)d_out;

    // workspace (~106 MiB)
    ushort* xb  = (ushort*)d_ws;                      // M*D bf16        (32 MiB)
    ushort* wzb = xb  + (size_t)M_*D_;                // L*H*D bf16      (4 MiB)
    ushort* whb = wzb + (size_t)L_*H_*D_;             // L*H*D bf16      (4 MiB)
    h2*     cv  = (h2*)(whb + (size_t)L_*H_*D_);      // M*H fp16x2      (64 MiB)
    float*  Ac  = (float*)(cv + (size_t)M_*H_);       // B*NC*H          (0.5 MiB)
    float*  Bc  = Ac + B_*NC*H_;
    float*  hin = Bc + B_*NC*H_;

    cast_f32_bf16<<<(M_*D_/4)/256, 256, 0, stream>>>(x, xb, M_*D_/4);
    cast_f32_bf16<<<(L_*H_*D_/4)/256, 256, 0, stream>>>(Wz, wzb, L_*H_*D_/4);
    cast_f32_bf16<<<(L_*H_*D_/4)/256, 256, 0, stream>>>(Wh, whb, L_*H_*D_/4);

    const int gemm_grid = (M_/128) * (H_/64);        // 128 * 16 = 2048 blocks
    for (int l = 0; l < L_; ++l) {
        gemm_fused<<<gemm_grid, 256, 0, stream>>>(xb,
                                                  wzb + (size_t)l*H_*D_,
                                                  whb + (size_t)l*H_*D_,
                                                  bz + l*H_, bh + l*H_,
                                                  cv, Ac, Bc);
        scan_chunk_combine<<<(B_*H_)/256, 256, 0, stream>>>(Ac, Bc, hin);
        scan_emit<<<(B_*NC*H_)/256, 256, 0, stream>>>(cv, hin, out, xb, (l == 0) ? 1 : 0);
    }
}

// Round 3
// 340.756 us; speedup vs baseline: 1.8519x; 1.3106x over previous
//
#include <hip/hip_runtime.h>
#include <hip/hip_bf16.h>

// MinGRU: L=2 layers of  h_t = (1-z_t) h_{t-1} + z_t g(pre_t)
// R3: + XOR-swizzled LDS (kills 16-way ds_read_b128 conflicts),
//     + XCD-aware block swizzle (A-tile L2 reuse),
//     + NC=32 chunks, vectorized (2h/thread) scan_emit.

#define L_ 2
#define B_ 8
#define S_ 2048
#define D_ 1024
#define H_ 1024
#define M_ (B_*S_)     // 16384
#define NC 32          // chunks per sequence
#define CL (S_/NC)     // 64 steps per chunk (GEMM m-tile 128 = 2 chunks)

typedef __bf16    bf16x8 __attribute__((ext_vector_type(8)));
typedef float     f32x4  __attribute__((ext_vector_type(4)));
typedef _Float16  h2     __attribute__((ext_vector_type(2)));
typedef _Float16  h4     __attribute__((ext_vector_type(4)));

__device__ __forceinline__ ushort f2bf(float f) {
    union { __hip_bfloat16 h; ushort u; } c;
    c.h = __float2bfloat16(f);   // RNE
    return c.u;
}

__device__ __forceinline__ void async16(const void* g, void* l) {
    __builtin_amdgcn_global_load_lds(
        (const __attribute__((address_space(1))) unsigned int*)g,
        (__attribute__((address_space(3))) unsigned int*)l, 16, 0, 0);
}

__global__ __launch_bounds__(256) void cast_f32_bf16(const float* __restrict__ in,
                                                     ushort* __restrict__ out, int n4) {
    int i = blockIdx.x * 256 + threadIdx.x;
    if (i >= n4) return;
    float4 v = ((const float4*)in)[i];
    ushort4 o;
    o.x = f2bf(v.x); o.y = f2bf(v.y); o.z = f2bf(v.z); o.w = f2bf(v.w);
    ((ushort4*)out)[i] = o;
}

// LDS layout: row R (64 ushorts = 8 chunks of 16B); logical chunk c stored at
// physical chunk c ^ (R&7).  Offset in ushorts:
#define SWZ(R, c) (((R) << 6) + ((((c) ^ ((R) & 7))) << 3))

// Fused: k = A@Wz^T+bz, pre = A@Wh^T+bh ; cv = (sigmoid(-k), sigmoid(k)*g(pre)) fp16x2.
// Tile 128m x 64n = 2 chunks of CL=64; epilogue composes both chunk affines -> Ac, Bc.
__global__ __launch_bounds__(256) void gemm_fused(const ushort* __restrict__ A,
                                                  const ushort* __restrict__ Wz,
                                                  const ushort* __restrict__ Wh,
                                                  const float* __restrict__ bz,
                                                  const float* __restrict__ bh,
                                                  h2* __restrict__ cv,
                                                  float* __restrict__ Ac,
                                                  float* __restrict__ Bc)
{
    __shared__ __align__(16) ushort sm[16384];       // 32 KiB
    ushort* As = sm;            // 128 x 64
    ushort* Zs = sm + 8192;     //  64 x 64
    ushort* Hs = sm + 12288;    //  64 x 64

    const int t    = threadIdx.x;
    const int lane = t & 63;
    const int wave = t >> 6;
    // XCD-aware swizzle: the 16 blocks sharing an A-tile (same mblk) get the same
    // blockIdx%8 -> same XCD L2.
    const int xcd = (int)blockIdx.x & 7;
    const int k8  = (int)blockIdx.x >> 3;            // 0..255
    const int nblk = k8 & 15;
    const int mblk = ((k8 >> 4) << 3) + xcd;         // 0..127
    const int m0 = mblk * 128;
    const int n0 = nblk * 64;
    const int wm = (wave >> 1) * 64;                 // 0 / 64
    const int wn = (wave & 1) * 32;                  // 0 / 32

    const int srow   = lane >> 3;                    // 0..7
    const int scol_g = (((lane & 7) ^ srow) << 3);   // swizzled source chunk

    f32x4 accz[4][2] = {};
    f32x4 acch[4][2] = {};
    const int lrow = lane & 15;
    const int lcq  = lane >> 4;                      // chunk sub-index 0..3

    for (int kb = 0; kb < D_; kb += 64) {
        __syncthreads();
        #pragma unroll
        for (int i = 0; i < 4; ++i) {                // A: 128 rows
            int r = i*32 + wave*8;
            async16(&A[(size_t)(m0 + r + srow)*D_ + kb + scol_g], &As[r*64]);
        }
        #pragma unroll
        for (int i = 0; i < 2; ++i) {                // Wz, Wh: 64 rows each
            int r = i*32 + wave*8;
            async16(&Wz[(size_t)(n0 + r + srow)*D_ + kb + scol_g], &Zs[r*64]);
            async16(&Wh[(size_t)(n0 + r + srow)*D_ + kb + scol_g], &Hs[r*64]);
        }
        __syncthreads();                             // drains vmcnt -> LDS valid
        #pragma unroll
        for (int kk = 0; kk < 64; kk += 32) {
            const int cq = (kk >> 3) + lcq;          // logical chunk 0..7
            bf16x8 af[4];
            #pragma unroll
            for (int mt = 0; mt < 4; ++mt) {
                int R = wm + mt*16 + lrow;
                uint4 u = *(const uint4*)&As[SWZ(R, cq)];
                af[mt] = __builtin_bit_cast(bf16x8, u);
            }
            #pragma unroll
            for (int nt = 0; nt < 2; ++nt) {
                int R = wn + nt*16 + lrow;
                uint4 uz = *(const uint4*)&Zs[SWZ(R, cq)];
                uint4 uh = *(const uint4*)&Hs[SWZ(R, cq)];
                bf16x8 zb = __builtin_bit_cast(bf16x8, uz);
                bf16x8 hb = __builtin_bit_cast(bf16x8, uh);
                #pragma unroll
                for (int mt = 0; mt < 4; ++mt) {
                    accz[mt][nt] = __builtin_amdgcn_mfma_f32_16x16x32_bf16(af[mt], zb, accz[mt][nt], 0, 0, 0);
                    acch[mt][nt] = __builtin_amdgcn_mfma_f32_16x16x32_bf16(af[mt], hb, acch[mt][nt], 0, 0, 0);
                }
            }
        }
    }

    __syncthreads();                                 // MFMA LDS reads done; reuse LDS
    float2* seg = (float2*)sm;                       // [32 segs][stride 65] float2

    // C/D layout [m89-verified]: col = lane&15, row = (lane>>4)*4 + reg
    const int colq = lane & 15;
    const int rowq = (lane >> 4) * 4;
    #pragma unroll
    for (int nt = 0; nt < 2; ++nt) {
        const int n = n0 + wn + nt*16 + colq;
        const float bzv = bz[n];
        const float bhv = bh[n];
        #pragma unroll
        for (int mt = 0; mt < 4; ++mt) {
            float a = 1.f, bb = 0.f;                 // affine over this lane's 4 rows
            #pragma unroll
            for (int r = 0; r < 4; ++r) {
                const int m = m0 + wm + mt*16 + rowq + r;
                float k = accz[mt][nt][r] + bzv;
                float p = acch[mt][nt][r] + bhv;
                float e   = __expf(-fabsf(k));
                float inv = 1.0f / (1.0f + e);
                float z   = (k >= 0.f) ? inv     : e * inv;
                float c   = (k >= 0.f) ? e * inv : inv;
                float g;
                if (p >= 0.f) g = p + 0.5f;
                else { float eg = __expf(p); g = eg / (1.0f + eg); }
                float v = z * g;
                h2 hv; hv[0] = (_Float16)c; hv[1] = (_Float16)v;
                cv[(size_t)m * H_ + n] = hv;
                bb = fmaf(c, bb, v);
                a *= c;
            }
            const int sidx = (wm >> 2) + mt*4 + (rowq >> 2);   // 0..31, time-ordered
            seg[sidx*65 + wn + nt*16 + colq] = make_float2(a, bb);
        }
    }
    __syncthreads();
    // two chunks of CL=64 per tile: segs 0..15 -> chunk 2*c0, segs 16..31 -> 2*c0+1
    if (t < 128) {
        const int col  = t & 63;
        const int half = t >> 6;
        float a = 1.f, bb = 0.f;
        #pragma unroll
        for (int s = 0; s < 16; ++s) {
            float2 e = seg[(half*16 + s)*65 + col];
            bb = fmaf(e.x, bb, e.y);
            a *= e.x;
        }
        const int b     = m0 >> 11;                  // S = 2048
        const int chunk = ((m0 >> 6) & (NC - 1)) + half;
        const int q = (b*NC + chunk)*H_ + n0 + col;
        Ac[q] = a; Bc[q] = bb;
    }
}

// Scan over the NC chunk-affines per (b,h); emit incoming h per chunk.
__global__ __launch_bounds__(256) void scan_chunk_combine(const float* __restrict__ Ac,
                                                          const float* __restrict__ Bc,
                                                          float* __restrict__ hin)
{
    int q = blockIdx.x * 256 + threadIdx.x;          // 0 .. B*H-1
    int h = q & (H_-1);
    int b = q >> 10;
    float hcur = 0.5f;                               // h0 = g(0) = 0.5
    #pragma unroll
    for (int c = 0; c < NC; ++c) {
        int idx = (b*NC + c)*H_ + h;
        hin[idx] = hcur;
        hcur = fmaf(Ac[idx], hcur, Bc[idx]);
    }
}

// Re-scan each chunk with known incoming h; 2 h-values per thread (8B loads).
__global__ __launch_bounds__(256) void scan_emit(const h2* __restrict__ cv,
                                                 const float* __restrict__ hin,
                                                 float* __restrict__ outf,
                                                 ushort* __restrict__ outb,
                                                 const int write_bf16)
{
    int q = blockIdx.x * 256 + threadIdx.x;          // 0 .. B*NC*H/2-1
    int hp = (q & 511) * 2;                          // h, h+1
    int c = (q >> 9) & (NC-1);
    int b = q >> 14;
    size_t base = (size_t)(b*S_ + c*CL) * H_ + hp;
    int qh = (b*NC + c)*H_ + hp;
    float h0 = hin[qh], h1 = hin[qh + 1];
    if (write_bf16) {
        #pragma unroll 4
        for (int tt = 0; tt < CL; ++tt) {
            h4 e = *(const h4*)&cv[base + (size_t)tt * H_];
            h0 = fmaf((float)e[0], h0, (float)e[1]);
            h1 = fmaf((float)e[2], h1, (float)e[3]);
            ushort2 o; o.x = f2bf(h0); o.y = f2bf(h1);
            *(ushort2*)&outb[base + (size_t)tt * H_] = o;
        }
    } else {
        #pragma unroll 4
        for (int tt = 0; tt < CL; ++tt) {
            h4 e = *(const h4*)&cv[base + (size_t)tt * H_];
            h0 = fmaf((float)e[0], h0, (float)e[1]);
            h1 = fmaf((float)e[2], h1, (float)e[3]);
            *(float2*)&outf[base + (size_t)tt * H_] = make_float2(h0, h1);
        }
    }
}

extern "C" void kernel_launch(void* const* d_in, const int* in_sizes, int n_in,
                              void* d_out, int out_size, void* d_ws, size_t ws_size,
                              hipStream_t stream)
{
    const float* x  = (const float*)d_in[0];
    const float* Wz = (const float*)d_in[1];
    const float* bz = (const float*)d_in[2];
    const float* Wh = (const float*)d_in[3];
    const float* bh = (const float*)d_in[4];
    float* out = (float*)d_out;

    // workspace (~107 MiB)
    ushort* xb  = (ushort*)d_ws;                      // M*D bf16        (32 MiB)
    ushort* wzb = xb  + (size_t)M_*D_;                // L*H*D bf16      (4 MiB)
    ushort* whb = wzb + (size_t)L_*H_*D_;             // L*H*D bf16      (4 MiB)
    h2*     cv  = (h2*)(whb + (size_t)L_*H_*D_);      // M*H fp16x2      (64 MiB)
    float*  Ac  = (float*)(cv + (size_t)M_*H_);       // B*NC*H          (1 MiB)
    float*  Bc  = Ac + B_*NC*H_;
    float*  hin = Bc + B_*NC*H_;

    cast_f32_bf16<<<(M_*D_/4)/256, 256, 0, stream>>>(x, xb, M_*D_/4);
    cast_f32_bf16<<<(L_*H_*D_/4)/256, 256, 0, stream>>>(Wz, wzb, L_*H_*D_/4);
    cast_f32_bf16<<<(L_*H_*D_/4)/256, 256, 0, stream>>>(Wh, whb, L_*H_*D_/4);

    const int gemm_grid = (M_/128) * (H_/64);        // 2048 blocks
    for (int l = 0; l < L_; ++l) {
        gemm_fused<<<gemm_grid, 256, 0, stream>>>(xb,
                                                  wzb + (size_t)l*H_*D_,
                                                  whb + (size_t)l*H_*D_,
                                                  bz + l*H_, bh + l*H_,
                                                  cv, Ac, Bc);
        scan_chunk_combine<<<(B_*H_)/256, 256, 0, stream>>>(Ac, Bc, hin);
        scan_emit<<<(B_*NC*H_/2)/256, 256, 0, stream>>>(cv, hin, out, xb, (l == 0) ? 1 : 0);
    }
}